// Round 10
// baseline (153.782 us; speedup 1.0000x reference)
//
#include <hip/hip_runtime.h>
#include <hip/hip_bf16.h>

#define IMG_W 1024
#define IMG_H 1024
#define TH    4            // output rows per block: 4096 blocks
#define VX    4            // pixels per thread (float4)
#define NTHREADS 256       // full row width per block

#define ALPHA_ 0.85f
#define BETA_  0.15f
#define C1_    (0.01f * 0.01f)
#define C2_    (0.03f * 0.03f)

// Sums-domain SSIM constants (numerator/denominator both scaled by 81).
#define K1_   (81.0f * C1_)          // 0.0081
#define K2_   (81.0f * C2_)          // 0.0729
#define K12_  (K1_ + K2_)            // 0.081

typedef float f32x4 __attribute__((ext_vector_type(4)));

// Inline-asm loads: the compiler cannot sink these (volatile, fixed order
// among themselves) and cannot collapse their "=v" outputs. This is the one
// form of software pipelining the register allocator provably can't undo
// (R1/R2/R4/R6: every compiler-level pipeline collapsed to VGPR<=92).
#define GLD4(dst, addr) \
    asm volatile("global_load_dwordx4 %0, %1, off" : "=v"(dst) : "v"(addr))
#define GLD1(dst, addr) \
    asm volatile("global_load_dword %0, %1, off" : "=v"(dst) : "v"(addr))

// Counted wait (T4: never 0 until the final row) + rule #18 fence:
// sched_barrier(0) right after, else hipcc hoists the pure-VALU consumers
// above the inline-asm waitcnt.
#define WAITV(n) do {                                          \
    asm volatile("s_waitcnt vmcnt(" #n ")" ::: "memory");      \
    __builtin_amdgcn_sched_barrier(0);                         \
} while (0)

// Per-row horizontal 3-sum stats for VX pixels: 20 floats.
struct RowS { float p[VX], t[VX], pp[VX], tt[VX], pt[VX]; };

__device__ __forceinline__ void rzero(RowS& h) {
#pragma unroll
    for (int j = 0; j < VX; ++j) {
        h.p[j] = 0.f; h.t[j] = 0.f; h.pp[j] = 0.f; h.tt[j] = 0.f; h.pt[j] = 0.f;
    }
}

__device__ __forceinline__ void hsum(const float pv[6], const float tv[6], RowS& h) {
#pragma unroll
    for (int j = 0; j < VX; ++j) {
        const float a = pv[j], b = pv[j + 1], c = pv[j + 2];
        const float u = tv[j], v = tv[j + 1], w = tv[j + 2];
        h.p[j]  = a + b + c;
        h.t[j]  = u + v + w;
        h.pp[j] = a * a + b * b + c * c;
        h.tt[j] = u * u + v * v + w * w;
        h.pt[j] = a * u + b * v + c * w;
    }
}

__device__ __forceinline__ void add_l1(const float pv[6], const float tv[6],
                                       float& l1_acc) {
#pragma unroll
    for (int k = 1; k <= VX; ++k) l1_acc += fabsf(pv[k] - tv[k]);
}

// Consume one row: emit SSIM for the output row above it and roll the
// vertical window state (AB = rowstats(y-1)+rowstats(y), Bp = rowstats(y)).
__device__ __forceinline__ void compute_row(const float pv[6], const float tv[6],
                                            RowS& AB, RowS& Bp, float& ssim_acc) {
#pragma unroll
    for (int j = 0; j < VX; ++j) {
        const float a = pv[j], b = pv[j + 1], c = pv[j + 2];
        const float u = tv[j], v = tv[j + 1], w = tv[j + 2];
        const float cp  = a + b + c;
        const float ct  = u + v + w;
        const float cpp = a * a + b * b + c * c;
        const float ctt = u * u + v * v + w * w;
        const float cpt = a * u + b * v + c * w;

        const float Sp  = AB.p[j]  + cp;
        const float St  = AB.t[j]  + ct;
        const float Spp = AB.pp[j] + cpp;
        const float Stt = AB.tt[j] + ctt;
        const float Spt = AB.pt[j] + cpt;

        AB.p[j]  = Bp.p[j]  + cp;  Bp.p[j]  = cp;
        AB.t[j]  = Bp.t[j]  + ct;  Bp.t[j]  = ct;
        AB.pp[j] = Bp.pp[j] + cpp; Bp.pp[j] = cpp;
        AB.tt[j] = Bp.tt[j] + ctt; Bp.tt[j] = ctt;
        AB.pt[j] = Bp.pt[j] + cpt; Bp.pt[j] = cpt;

        // sums-domain SSIM (x81^2 in both numerator and denominator)
        const float SpSt = Sp * St;
        const float A2 = fmaf(2.0f, SpSt, K1_);
        const float B2 = fmaf(-2.0f, SpSt, fmaf(18.0f, Spt, K2_));
        const float n  = A2 * B2;
        const float D1 = fmaf(Sp, Sp, fmaf(St, St, K1_));
        const float D2 = fmaf(9.0f, Spp + Stt, K12_) - D1;
        const float d  = D1 * D2;
        const float ssim = n * __builtin_amdgcn_rcpf(d);  // d >= 81^2*C1*C2 > 0
        float vcl = fmaf(-0.5f, ssim, 0.5f);
        vcl = fminf(fmaxf(vcl, 0.0f), 1.0f);
        ssim_acc += vcl;
    }
}

// R10 (= R9 resubmit, hardened): inline-asm forced load pipeline (AITER T4
// pattern at HIP level). 36 loads (6 rows x 2 tensors x {body dwordx4, left
// dword, right dword}) issued back-to-back as volatile asm -> ~4.5 KB per
// lane-group in flight, unkillable by the register allocator. Consumed in
// issue order with hand-counted s_waitcnt vmcnt(30/24/18/12/6/0). No LDS
// staging, no workgroup barriers in the main loop. XCD-chunked bijective
// swizzle and sums-domain SSIM kept (proven). All 36 loads are issued
// UNCONDITIONALLY (clamped addresses) so the per-wave vmcnt count is exact
// (no compiler-emitted VMEM ops exist between issue and the last wait).
// HARDENING vs R9: __launch_bounds__(NTHREADS, 1) grants the allocator the
// full register budget so a PENDING asm-load output can never be spilled
// (the backend cannot see that hazard; a spill would read the register
// before the async load lands).
template <int MODE>
__global__ void __launch_bounds__(NTHREADS, 1)
ssim_l1_kernel(const float* __restrict__ pred, const float* __restrict__ tgt,
               float* __restrict__ ws) {
    const int tid = threadIdx.x;
    const int x   = tid * VX;

    // XCD-chunked swizzle: 4096 % 8 == 0 -> bijective.
    const int nyt     = IMG_H / TH;                 // 256 y-tiles per image
    const int per_xcd = gridDim.x >> 3;             // 512
    const int lin     = (blockIdx.x & 7) * per_xcd + (blockIdx.x >> 3);
    const int img     = lin / nyt;
    const int yt      = lin - img * nyt;
    const int y0      = yt * TH;

    const size_t base = (size_t)img * (size_t)(IMG_W * IMG_H);
    const float* __restrict__ P = pred + base;
    const float* __restrict__ T = tgt + base;

    // Clamped halo-column ADDRESSES (values zero-fixed at consume).
    const int xl = (x > 0) ? x - 1 : 0;
    const int xr = (x + VX < IMG_W) ? x + VX : IMG_W - 1;

    // 36 named asm-load destinations (6 rows x {pb,pl,pr,tb,tl,tr}).
    f32x4 pb0, pb1, pb2, pb3, pb4, pb5;
    f32x4 tb0, tb1, tb2, tb3, tb4, tb5;
    float pl0, pl1, pl2, pl3, pl4, pl5;
    float pr0, pr1, pr2, pr3, pr4, pr5;
    float tl0, tl1, tl2, tl3, tl4, tl5;
    float tr0, tr1, tr2, tr3, tr4, tr5;

#define ISSUE_ROW(k, ry) do {                                        \
    const float* rp_ = P + (size_t)(ry) * IMG_W;                     \
    const float* rt_ = T + (size_t)(ry) * IMG_W;                     \
    GLD4(pb##k, rp_ + x); GLD1(pl##k, rp_ + xl); GLD1(pr##k, rp_ + xr); \
    GLD4(tb##k, rt_ + x); GLD1(tl##k, rt_ + xl); GLD1(tr##k, rt_ + xr); \
} while (0)

    // ---- issue phase: all 36 loads, zero waits ----
    ISSUE_ROW(0, (y0 > 0) ? y0 - 1 : 0);                       // top halo (clamped)
    ISSUE_ROW(1, y0);
    ISSUE_ROW(2, y0 + 1);
    ISSUE_ROW(3, y0 + 2);
    ISSUE_ROW(4, y0 + 3);
    ISSUE_ROW(5, (y0 + TH < IMG_H) ? y0 + TH : IMG_H - 1);     // bottom halo (clamped)
#undef ISSUE_ROW

#define EXPAND(k)                                                     \
    pv[0] = (x == 0) ? 0.f : pl##k;                                   \
    pv[1] = pb##k.x; pv[2] = pb##k.y; pv[3] = pb##k.z; pv[4] = pb##k.w; \
    pv[5] = (x + VX >= IMG_W) ? 0.f : pr##k;                          \
    tv[0] = (x == 0) ? 0.f : tl##k;                                   \
    tv[1] = tb##k.x; tv[2] = tb##k.y; tv[3] = tb##k.z; tv[4] = tb##k.w; \
    tv[5] = (x + VX >= IMG_W) ? 0.f : tr##k;

    float ssim_acc = 0.f, l1_acc = 0.f;
    RowS AB, Bp;
    float pv[6], tv[6];

    // ---- consume phase: issue order, counted waits (never 0 until last) ----
    WAITV(30);                         // row 0 (loads 0..5) landed
    if (y0 > 0) {
        EXPAND(0);
        hsum(pv, tv, AB);
    } else {
        rzero(AB);
    }

    WAITV(24);                         // row 1 landed
    EXPAND(1);
    hsum(pv, tv, Bp);
    add_l1(pv, tv, l1_acc);
#pragma unroll
    for (int j = 0; j < VX; ++j) {
        AB.p[j]  += Bp.p[j];  AB.t[j]  += Bp.t[j];
        AB.pp[j] += Bp.pp[j]; AB.tt[j] += Bp.tt[j]; AB.pt[j] += Bp.pt[j];
    }

    WAITV(18);                         // row 2 landed
    EXPAND(2);
    add_l1(pv, tv, l1_acc);
    compute_row(pv, tv, AB, Bp, ssim_acc);     // out row y0

    WAITV(12);                         // row 3 landed
    EXPAND(3);
    add_l1(pv, tv, l1_acc);
    compute_row(pv, tv, AB, Bp, ssim_acc);     // out row y0+1

    WAITV(6);                          // row 4 landed
    EXPAND(4);
    add_l1(pv, tv, l1_acc);
    compute_row(pv, tv, AB, Bp, ssim_acc);     // out row y0+2

    WAITV(0);                          // row 5 landed (final drain)
    if (y0 + TH < IMG_H) {
        EXPAND(5);
    } else {
#pragma unroll
        for (int k = 0; k < 6; ++k) { pv[k] = 0.f; tv[k] = 0.f; }
    }
    compute_row(pv, tv, AB, Bp, ssim_acc);     // out row y0+3 (halo: no l1)
#undef EXPAND

    // --- reduction: wave shuffle -> LDS across 4 waves -> one write/block ---
    float s = ssim_acc, l = l1_acc;
#pragma unroll
    for (int off = 32; off > 0; off >>= 1) {
        s += __shfl_down(s, off, 64);
        l += __shfl_down(l, off, 64);
    }
    __shared__ float red_s[NTHREADS / 64];
    __shared__ float red_l[NTHREADS / 64];
    const int wid = tid >> 6, lane = tid & 63;
    if (lane == 0) { red_s[wid] = s; red_l[wid] = l; }
    __syncthreads();
    if (tid == 0) {
        float ss = 0.f, ll = 0.f;
#pragma unroll
        for (int w = 0; w < NTHREADS / 64; ++w) { ss += red_s[w]; ll += red_l[w]; }
        if (MODE == 0) {
            ws[2 * lin]     = ss;      // lin bijective: every slot written
            ws[2 * lin + 1] = ll;
        } else {
            atomicAdd(&ws[0], ss);
            atomicAdd(&ws[1], ll);
        }
    }
}

__global__ void zero_ws_kernel(float* __restrict__ ws) {
    ws[0] = 0.f;
    ws[1] = 0.f;
}

// Sum nblocks (ssim,l1) pairs from ws and emit the final scalar.
__global__ void __launch_bounds__(256)
finalize_partials_kernel(const float* __restrict__ ws, float* __restrict__ out,
                         int nblocks, float inv_total) {
    const int tid = threadIdx.x;
    float s = 0.f, l = 0.f;
    for (int i = tid; i < nblocks; i += 256) {
        s += ws[2 * i];
        l += ws[2 * i + 1];
    }
#pragma unroll
    for (int off = 32; off > 0; off >>= 1) {
        s += __shfl_down(s, off, 64);
        l += __shfl_down(l, off, 64);
    }
    __shared__ float red_s[4], red_l[4];
    const int wid = tid >> 6, lane = tid & 63;
    if (lane == 0) { red_s[wid] = s; red_l[wid] = l; }
    __syncthreads();
    if (tid == 0) {
        float ss = red_s[0] + red_s[1] + red_s[2] + red_s[3];
        float ll = red_l[0] + red_l[1] + red_l[2] + red_l[3];
        out[0] = ALPHA_ * (ss * inv_total) + BETA_ * (ll * inv_total);
    }
}

__global__ void finalize_atomic_kernel(const float* __restrict__ ws,
                                       float* __restrict__ out, float inv_total) {
    out[0] = ALPHA_ * (ws[0] * inv_total) + BETA_ * (ws[1] * inv_total);
}

extern "C" void kernel_launch(void* const* d_in, const int* in_sizes, int n_in,
                              void* d_out, int out_size, void* d_ws, size_t ws_size,
                              hipStream_t stream) {
    const float* pred = (const float*)d_in[0];
    const float* tgt  = (const float*)d_in[1];
    float* ws = (float*)d_ws;

    const int total = in_sizes[0];                 // N * H * W = 16 * 1024 * 1024
    const int nimg  = total / (IMG_W * IMG_H);     // 16
    const int nblk  = nimg * (IMG_H / TH);         // 16 * 256 = 4096
    const float inv_total = 1.0f / (float)total;

    dim3 grid(nblk, 1, 1);                         // 1D for XCD swizzle

    if (ws_size >= (size_t)(2 * nblk) * sizeof(float)) {
        // partials path: no pre-zero, no atomics
        ssim_l1_kernel<0><<<grid, NTHREADS, 0, stream>>>(pred, tgt, ws);
        finalize_partials_kernel<<<1, 256, 0, stream>>>(ws, (float*)d_out,
                                                        nblk, inv_total);
    } else {
        // fallback: atomic accumulation into ws[0..1]
        zero_ws_kernel<<<1, 1, 0, stream>>>(ws);
        ssim_l1_kernel<1><<<grid, NTHREADS, 0, stream>>>(pred, tgt, ws);
        finalize_atomic_kernel<<<1, 1, 0, stream>>>(ws, (float*)d_out, inv_total);
    }
}